// Round 2
// baseline (479.603 us; speedup 1.0000x reference)
//
#include <hip/hip_runtime.h>

#define NROWS 65536
#define DM 128

// ws layout in floats
#define WS_CKV  0        // 128*128 Gram matrix (atomic-accumulated)
#define WS_SKEY 16384    // 128 col sums of key
#define WS_SVAL 16512    // 128 col sums of value
#define WS_W2   16640    // 128*128 folded phase-2 weight
#define WS_B2   33024    // 128 folded phase-2 bias
#define WS_ZERO_FLOATS 16640   // Ckv + skey + sval must start at 0

// ---------------------------------------------------------------------------
// Kernel A: C = key^T @ value (128x128 fp32), plus column sums s_key, s_val.
// 256 blocks x 512 threads; each block owns 256 rows, accumulates a full
// 128x128 tile (32 acc/thread), double-buffered 32-row LDS staging,
// atomicAdd reduction into ws.
// ---------------------------------------------------------------------------
__global__ __launch_bounds__(512, 2) void kernelA(const float* __restrict__ key,
                                                  const float* __restrict__ value,
                                                  float* __restrict__ ws) {
    __shared__ float lk[2][32 * 128];
    __shared__ float lv[2][32 * 128];
    __shared__ float red[128];

    const int tid = threadIdx.x;
    const int i0 = (tid >> 4) * 4;   // 0..124
    const int j0 = (tid & 15) * 8;   // 0..120
    const int row0 = blockIdx.x * 256;

    const float4* __restrict__ k4 = (const float4*)key;
    const float4* __restrict__ v4 = (const float4*)value;

    float acc[4][8];
#pragma unroll
    for (int a = 0; a < 4; ++a)
#pragma unroll
        for (int b = 0; b < 8; ++b) acc[a][b] = 0.f;

    float sk[4] = {0.f, 0.f, 0.f, 0.f};
    float sv[4] = {0.f, 0.f, 0.f, 0.f};

    float4 rk0, rk1, rv0, rv1;
    // prologue: tile 0
    {
        const int g = row0 * 32;
        rk0 = k4[g + tid]; rk1 = k4[g + tid + 512];
        rv0 = v4[g + tid]; rv1 = v4[g + tid + 512];
        ((float4*)lk[0])[tid] = rk0; ((float4*)lk[0])[tid + 512] = rk1;
        ((float4*)lv[0])[tid] = rv0; ((float4*)lv[0])[tid + 512] = rv1;
        sk[0] += rk0.x + rk1.x; sk[1] += rk0.y + rk1.y; sk[2] += rk0.z + rk1.z; sk[3] += rk0.w + rk1.w;
        sv[0] += rv0.x + rv1.x; sv[1] += rv0.y + rv1.y; sv[2] += rv0.z + rv1.z; sv[3] += rv0.w + rv1.w;
    }
    __syncthreads();

    for (int t = 0; t < 8; ++t) {
        const int cur = t & 1;
        if (t < 7) {  // issue next-tile global loads early (hide HBM latency)
            const int g = (row0 + (t + 1) * 32) * 32;
            rk0 = k4[g + tid]; rk1 = k4[g + tid + 512];
            rv0 = v4[g + tid]; rv1 = v4[g + tid + 512];
        }
#pragma unroll 4
        for (int kk = 0; kk < 32; ++kk) {
            float ka[4], vb[8];
            *(float4*)&ka[0] = *(const float4*)&lk[cur][kk * 128 + i0];
            *(float4*)&vb[0] = *(const float4*)&lv[cur][kk * 128 + j0];
            *(float4*)&vb[4] = *(const float4*)&lv[cur][kk * 128 + j0 + 4];
#pragma unroll
            for (int a = 0; a < 4; ++a)
#pragma unroll
                for (int b = 0; b < 8; ++b)
                    acc[a][b] = fmaf(ka[a], vb[b], acc[a][b]);
        }
        if (t < 7) {
            const int nxt = cur ^ 1;
            ((float4*)lk[nxt])[tid] = rk0; ((float4*)lk[nxt])[tid + 512] = rk1;
            ((float4*)lv[nxt])[tid] = rv0; ((float4*)lv[nxt])[tid + 512] = rv1;
            sk[0] += rk0.x + rk1.x; sk[1] += rk0.y + rk1.y; sk[2] += rk0.z + rk1.z; sk[3] += rk0.w + rk1.w;
            sv[0] += rv0.x + rv1.x; sv[1] += rv0.y + rv1.y; sv[2] += rv0.z + rv1.z; sv[3] += rv0.w + rv1.w;
            __syncthreads();
        }
    }

    // reduce Gram tile into global ws
#pragma unroll
    for (int a = 0; a < 4; ++a)
#pragma unroll
        for (int b = 0; b < 8; ++b)
            atomicAdd(&ws[WS_CKV + (i0 + a) * 128 + (j0 + b)], acc[a][b]);

    // column sums: thread's loaded columns are (tid&31)*4 .. +3
    const int cg = (tid & 31) * 4;
    __syncthreads();
    if (tid < 128) red[tid] = 0.f;
    __syncthreads();
#pragma unroll
    for (int a = 0; a < 4; ++a) atomicAdd(&red[cg + a], sk[a]);
    __syncthreads();
    if (tid < 128) atomicAdd(&ws[WS_SKEY + tid], red[tid]);
    __syncthreads();
    if (tid < 128) red[tid] = 0.f;
    __syncthreads();
#pragma unroll
    for (int a = 0; a < 4; ++a) atomicAdd(&red[cg + a], sv[a]);
    __syncthreads();
    if (tid < 128) atomicAdd(&ws[WS_SVAL + tid], red[tid]);
}

// ---------------------------------------------------------------------------
// Kernel B: per-head (4 blocks x 256 threads):
//   T = C @ Wv_h^T            (128 x 32)
//   p_h[d][e] = (Wk_h T + (Wk_h s_k) bv^T + bk (Wv_h s_v)^T + N bk bv^T)/N
//   W2[:, h*32+e] = sum_d Wq[h*32+d,:] p_h[d][e];  b2 = bq_h @ p_h
// Writes p_attn to out tail and W2/b2 to ws.
// ---------------------------------------------------------------------------
__global__ void kernelB(const float* __restrict__ Wk, const float* __restrict__ bk,
                        const float* __restrict__ Wv, const float* __restrict__ bv,
                        const float* __restrict__ Wq, const float* __restrict__ bq,
                        float* __restrict__ ws, float* __restrict__ out) {
    __shared__ float ckv[128 * 128];  // [i][j]
    __shared__ float wvT[128 * 32];   // [j][e]
    __shared__ float wk_s[32 * 128];  // [d][i]
    __shared__ float wq_s[32 * 128];  // [d][i]
    __shared__ float Tl[128 * 32];    // [i][e]
    __shared__ float pl[32 * 32];     // [d][e]
    __shared__ float skey[128], sval[128];
    __shared__ float bk_s[32], bv_s[32], bq_s[32];
    __shared__ float wvec[32], uvec[32];

    const int tid = threadIdx.x;
    const int h = blockIdx.x;

    const float4* __restrict__ ws4 = (const float4*)ws;
    const float4* __restrict__ Wk4 = (const float4*)Wk;
    const float4* __restrict__ Wq4 = (const float4*)Wq;
    const float4* __restrict__ Wv4 = (const float4*)Wv;

#pragma unroll
    for (int q = 0; q < 16; ++q)
        ((float4*)ckv)[tid + 256 * q] = ws4[(WS_CKV >> 2) + tid + 256 * q];
#pragma unroll
    for (int q = 0; q < 4; ++q) {
        ((float4*)wk_s)[tid + 256 * q] = Wk4[h * 1024 + tid + 256 * q];
        ((float4*)wq_s)[tid + 256 * q] = Wq4[h * 1024 + tid + 256 * q];
    }
#pragma unroll
    for (int q = 0; q < 4; ++q) {
        const int f = tid + 256 * q;
        const int e = f >> 5;
        const int c = (f & 31) * 4;
        float4 v = Wv4[h * 1024 + f];
        wvT[(c + 0) * 32 + e] = v.x;
        wvT[(c + 1) * 32 + e] = v.y;
        wvT[(c + 2) * 32 + e] = v.z;
        wvT[(c + 3) * 32 + e] = v.w;
    }
    if (tid < 128) { skey[tid] = ws[WS_SKEY + tid]; sval[tid] = ws[WS_SVAL + tid]; }
    if (tid < 32) { bk_s[tid] = bk[h * 32 + tid]; bv_s[tid] = bv[h * 32 + tid]; bq_s[tid] = bq[h * 32 + tid]; }
    __syncthreads();

    const int e = tid & 31;
    const int ib = (tid >> 5) * 16;
    {
        float accT[16] = {};
        for (int j = 0; j < 128; ++j) {
            const float wv = wvT[j * 32 + e];
#pragma unroll
            for (int ii = 0; ii < 16; ++ii)
                accT[ii] = fmaf(ckv[(ib + ii) * 128 + j], wv, accT[ii]);
        }
#pragma unroll
        for (int ii = 0; ii < 16; ++ii) Tl[(ib + ii) * 32 + e] = accT[ii];

        if (tid < 32) {
            float u = 0.f;
            for (int j = 0; j < 128; ++j) u = fmaf(wvT[j * 32 + tid], sval[j], u);
            uvec[tid] = u;
        } else if (tid < 64) {
            const int a = tid - 32;
            float w = 0.f;
            for (int i = 0; i < 128; ++i) w = fmaf(wk_s[a * 128 + i], skey[i], w);
            wvec[a] = w;
        }
    }
    __syncthreads();
    {
        const int d0 = tid >> 5;  // 0..7
        float accP[4] = {};
        for (int i = 0; i < 128; ++i) {
            const float tv = Tl[i * 32 + e];
#pragma unroll
            for (int r = 0; r < 4; ++r)
                accP[r] = fmaf(wk_s[(d0 + 8 * r) * 128 + i], tv, accP[r]);
        }
#pragma unroll
        for (int r = 0; r < 4; ++r) {
            const int d = d0 + 8 * r;
            const float p = (accP[r] + wvec[d] * bv_s[e] + bk_s[d] * uvec[e] +
                             65536.f * bk_s[d] * bv_s[e]) * (1.f / 65536.f);
            pl[d * 32 + e] = p;
            out[8388608 + h * 1024 + d * 32 + e] = p;
        }
    }
    __syncthreads();
    {
        float accW[16] = {};
        for (int d = 0; d < 32; ++d) {
            const float pv = pl[d * 32 + e];
#pragma unroll
            for (int ii = 0; ii < 16; ++ii)
                accW[ii] = fmaf(wq_s[d * 128 + (ib + ii)], pv, accW[ii]);
        }
#pragma unroll
        for (int ii = 0; ii < 16; ++ii)
            ws[WS_W2 + (ib + ii) * 128 + h * 32 + e] = accW[ii];

        if (tid < 32) {
            float b2v = 0.f;
#pragma unroll
            for (int d = 0; d < 32; ++d) b2v = fmaf(bq_s[d], pl[d * 32 + tid], b2v);
            ws[WS_B2 + h * 32 + tid] = b2v;
        }
    }
}

// ---------------------------------------------------------------------------
// Kernel C: x = query @ W2 + b2, stored transposed: out[c*65536 + n] = x[n][c].
// 256 blocks x 512 threads; 256 rows/block; k-chunked (16) double-buffered LDS
// with transposed q staging ([k][n]) so fragment reads are n-contiguous.
// ---------------------------------------------------------------------------
__global__ __launch_bounds__(512, 2) void kernelC(const float* __restrict__ query,
                                                  const float* __restrict__ ws,
                                                  float* __restrict__ out) {
    __shared__ float qT[2][16][256];
    __shared__ float w2s[2][16][128];
    __shared__ float b2s[128];

    const int tid = threadIdx.x;
    const int n0 = (tid >> 4) * 8;  // 0..248
    const int c0 = (tid & 15) * 8;  // 0..120
    const int rowbase = blockIdx.x * 256;
    const int nrow = tid >> 1;
    const int half = tid & 1;

    const float4* __restrict__ q4 = (const float4*)query;
    const float4* __restrict__ w24 = (const float4*)(ws + WS_W2);

    if (tid < 32) ((float4*)b2s)[tid] = ((const float4*)(ws + WS_B2))[tid];

    float acc[8][8];
#pragma unroll
    for (int a = 0; a < 8; ++a)
#pragma unroll
        for (int b = 0; b < 8; ++b) acc[a][b] = 0.f;

    float4 rq0, rq1, rw;
    // prologue: kc = 0
    rq0 = q4[(rowbase + nrow) * 32 + half * 2 + 0];
    rq1 = q4[(rowbase + nrow) * 32 + half * 2 + 1];
    rw = w24[tid];
    {
        const int kp = half * 8;
        qT[0][kp + 0][nrow] = rq0.x; qT[0][kp + 1][nrow] = rq0.y;
        qT[0][kp + 2][nrow] = rq0.z; qT[0][kp + 3][nrow] = rq0.w;
        qT[0][kp + 4][nrow] = rq1.x; qT[0][kp + 5][nrow] = rq1.y;
        qT[0][kp + 6][nrow] = rq1.z; qT[0][kp + 7][nrow] = rq1.w;
        ((float4*)w2s[0])[tid] = rw;
    }
    __syncthreads();

    for (int kc = 0; kc < 8; ++kc) {
        const int cur = kc & 1;
        if (kc < 7) {
            rq0 = q4[(rowbase + nrow) * 32 + (kc + 1) * 4 + half * 2 + 0];
            rq1 = q4[(rowbase + nrow) * 32 + (kc + 1) * 4 + half * 2 + 1];
            rw = w24[(kc + 1) * 512 + tid];
        }
#pragma unroll
        for (int k = 0; k < 16; ++k) {
            float qa[8], wb[8];
            *(float4*)&qa[0] = *(const float4*)&qT[cur][k][n0];
            *(float4*)&qa[4] = *(const float4*)&qT[cur][k][n0 + 4];
            *(float4*)&wb[0] = *(const float4*)&w2s[cur][k][c0];
            *(float4*)&wb[4] = *(const float4*)&w2s[cur][k][c0 + 4];
#pragma unroll
            for (int a = 0; a < 8; ++a)
#pragma unroll
                for (int b = 0; b < 8; ++b)
                    acc[a][b] = fmaf(qa[a], wb[b], acc[a][b]);
        }
        if (kc < 7) {
            const int nxt = cur ^ 1;
            const int kp = half * 8;
            qT[nxt][kp + 0][nrow] = rq0.x; qT[nxt][kp + 1][nrow] = rq0.y;
            qT[nxt][kp + 2][nrow] = rq0.z; qT[nxt][kp + 3][nrow] = rq0.w;
            qT[nxt][kp + 4][nrow] = rq1.x; qT[nxt][kp + 5][nrow] = rq1.y;
            qT[nxt][kp + 6][nrow] = rq1.z; qT[nxt][kp + 7][nrow] = rq1.w;
            ((float4*)w2s[nxt])[tid] = rw;
            __syncthreads();
        }
    }

#pragma unroll
    for (int b = 0; b < 8; ++b) {
        const int c = c0 + b;
        const float bb = b2s[c];
        float4 s0, s1;
        s0.x = acc[0][b] + bb; s0.y = acc[1][b] + bb; s0.z = acc[2][b] + bb; s0.w = acc[3][b] + bb;
        s1.x = acc[4][b] + bb; s1.y = acc[5][b] + bb; s1.z = acc[6][b] + bb; s1.w = acc[7][b] + bb;
        float* col = out + (size_t)c * 65536 + rowbase + n0;
        *(float4*)(col) = s0;
        *(float4*)(col + 4) = s1;
    }
}

extern "C" void kernel_launch(void* const* d_in, const int* in_sizes, int n_in,
                              void* d_out, int out_size, void* d_ws, size_t ws_size,
                              hipStream_t stream) {
    const float* query = (const float*)d_in[0];
    const float* key   = (const float*)d_in[1];
    const float* value = (const float*)d_in[2];
    const float* Wq = (const float*)d_in[3];
    const float* bq = (const float*)d_in[4];
    const float* Wk = (const float*)d_in[5];
    const float* bk = (const float*)d_in[6];
    const float* Wv = (const float*)d_in[7];
    const float* bv = (const float*)d_in[8];
    float* out = (float*)d_out;
    float* ws  = (float*)d_ws;

    (void)hipMemsetAsync(d_ws, 0, WS_ZERO_FLOATS * sizeof(float), stream);
    hipLaunchKernelGGL(kernelA, dim3(256), dim3(512), 0, stream, key, value, ws);
    hipLaunchKernelGGL(kernelB, dim3(4), dim3(256), 0, stream, Wk, bk, Wv, bv, Wq, bq, ws, out);
    hipLaunchKernelGGL(kernelC, dim3(256), dim3(512), 0, stream, query, ws, out);
}